// Round 11
// baseline (731.605 us; speedup 1.0000x reference)
//
#include <hip/hip_runtime.h>
#include <hip/hip_bf16.h>

#define N0 40000
#define N1 10000
#define N2 2500
#define N3 625
#define E0 240000
#define CIN 64
#define CH 256
#define NBLK ((N0 + 255) / 256)   // 157 scan blocks

// ---------------- degree / CSR build ----------------
__global__ void count_deg(const int* __restrict__ dst, int* __restrict__ deg, int e) {
    int i = blockIdx.x * blockDim.x + threadIdx.x;
    if (i < e) atomicAdd(&deg[dst[i]], 1);
}

// device-wide scan, stage 1: per-block inclusive scan + block sums
__global__ __launch_bounds__(256) void scan_blocks(const int* __restrict__ deg,
                                                   int* __restrict__ incl,
                                                   int* __restrict__ bsum, int n) {
    __shared__ int s[256];
    int i = blockIdx.x * 256 + threadIdx.x;
    s[threadIdx.x] = (i < n) ? deg[i] : 0;
    __syncthreads();
#pragma unroll
    for (int off = 1; off < 256; off <<= 1) {
        int t = (threadIdx.x >= off) ? s[threadIdx.x - off] : 0;
        __syncthreads();
        s[threadIdx.x] += t;
        __syncthreads();
    }
    if (i < n) incl[i] = s[threadIdx.x];
    if (threadIdx.x == 255) bsum[blockIdx.x] = s[255];
}

// stage 2: single-block inclusive scan of the block sums (NBLK <= 256)
__global__ __launch_bounds__(256) void scan_bsums(int* __restrict__ bsum, int nb) {
    __shared__ int s[256];
    s[threadIdx.x] = (threadIdx.x < nb) ? bsum[threadIdx.x] : 0;
    __syncthreads();
#pragma unroll
    for (int off = 1; off < 256; off <<= 1) {
        int t = (threadIdx.x >= off) ? s[threadIdx.x - off] : 0;
        __syncthreads();
        s[threadIdx.x] += t;
        __syncthreads();
    }
    if (threadIdx.x < nb) bsum[threadIdx.x] = s[threadIdx.x];
}

// stage 3: rowptr[0]=0; rowptr[i+1] = incl[i] + prefix(block sums)
__global__ void finalize_rowptr(const int* __restrict__ incl, const int* __restrict__ bsum,
                                int* __restrict__ rowptr, int n) {
    int i = blockIdx.x * blockDim.x + threadIdx.x;
    if (i == 0) rowptr[0] = 0;
    if (i < n) {
        int b = i >> 8;
        int off = b ? bsum[b - 1] : 0;
        rowptr[i + 1] = incl[i] + off;
    }
}

__global__ void copy_int(const int* __restrict__ a, int* __restrict__ b, int n) {
    int i = blockIdx.x * blockDim.x + threadIdx.x;
    if (i < n) b[i] = a[i];
}
__global__ void fill_csr(const int* __restrict__ src, const int* __restrict__ dst,
                         int* __restrict__ cursor, int* __restrict__ colsrc, int e) {
    int i = blockIdx.x * blockDim.x + threadIdx.x;
    if (i < e) {
        int d = dst[i];
        int p = atomicAdd(&cursor[d], 1);
        colsrc[p] = src[i];
    }
}
__global__ void make_inv(const int* __restrict__ deg, double* __restrict__ inv, int n) {
    int i = blockIdx.x * blockDim.x + threadIdx.x;
    if (i < n) inv[i] = 1.0 / sqrt((double)(deg[i] + 1));  // +1 self loop
}

// ---------------- f32 GEMM: 128x128 tile, 8x8 microtile (2x2 quadrants of 4x4) ----------------
// out[M x 256] = A[gidx[M] x K] @ W[K x 256] (+bias)
__global__ __launch_bounds__(256) void gemm_f32(
    const float* __restrict__ A, const int* __restrict__ gidx,
    const float* __restrict__ W, const float* __restrict__ bias,
    float* __restrict__ out, int M, int K)
{
    __shared__ float As[16][132];   // [k][row]
    __shared__ float Bs[16][132];   // [k][col]
    const int tid = threadIdx.x;
    const int tx = tid & 15, ty = tid >> 4;
    const int row0 = blockIdx.x * 128, col0 = blockIdx.y * 128;
    // A staging: 512 float4 / iter; thread t handles #t (rows 0..63) and #(t+256) (rows 64..127)
    const int sr = tid >> 2;            // 0..63
    const int skq = (tid & 3) * 4;      // k-quad
    const int ar0 = row0 + sr, ar1 = row0 + 64 + sr;
    const bool ok0 = ar0 < M, ok1 = ar1 < M;
    long g0 = 0, g1 = 0;
    if (ok0) g0 = (long)(gidx ? gidx[ar0] : ar0) * K;
    if (ok1) g1 = (long)(gidx ? gidx[ar1] : ar1) * K;
    // B staging: thread t handles k-rows bkk and bkk+8
    const int bkk = tid >> 5;           // 0..7
    const int bc4 = (tid & 31) * 4;     // 0..124

    float acc[2][2][4][4] = {};
    for (int k0 = 0; k0 < K; k0 += 16) {
        float4 av0 = make_float4(0.f, 0.f, 0.f, 0.f);
        float4 av1 = make_float4(0.f, 0.f, 0.f, 0.f);
        if (ok0) av0 = *reinterpret_cast<const float4*>(&A[g0 + k0 + skq]);
        if (ok1) av1 = *reinterpret_cast<const float4*>(&A[g1 + k0 + skq]);
        float4 bv0 = *reinterpret_cast<const float4*>(&W[(long)(k0 + bkk) * CH + col0 + bc4]);
        float4 bv1 = *reinterpret_cast<const float4*>(&W[(long)(k0 + bkk + 8) * CH + col0 + bc4]);
        As[skq + 0][sr] = av0.x;  As[skq + 1][sr] = av0.y;
        As[skq + 2][sr] = av0.z;  As[skq + 3][sr] = av0.w;
        As[skq + 0][64 + sr] = av1.x;  As[skq + 1][64 + sr] = av1.y;
        As[skq + 2][64 + sr] = av1.z;  As[skq + 3][64 + sr] = av1.w;
        *reinterpret_cast<float4*>(&Bs[bkk][bc4]) = bv0;
        *reinterpret_cast<float4*>(&Bs[bkk + 8][bc4]) = bv1;
        __syncthreads();
#pragma unroll
        for (int kk = 0; kk < 16; ++kk) {
            float4 a0 = *reinterpret_cast<const float4*>(&As[kk][ty * 4]);
            float4 a1 = *reinterpret_cast<const float4*>(&As[kk][64 + ty * 4]);
            float4 b0 = *reinterpret_cast<const float4*>(&Bs[kk][tx * 4]);
            float4 b1 = *reinterpret_cast<const float4*>(&Bs[kk][64 + tx * 4]);
            float ar[2][4] = {{a0.x, a0.y, a0.z, a0.w}, {a1.x, a1.y, a1.z, a1.w}};
            float br[2][4] = {{b0.x, b0.y, b0.z, b0.w}, {b1.x, b1.y, b1.z, b1.w}};
#pragma unroll
            for (int rh = 0; rh < 2; ++rh)
#pragma unroll
                for (int ch = 0; ch < 2; ++ch)
#pragma unroll
                    for (int i = 0; i < 4; ++i)
#pragma unroll
                        for (int j = 0; j < 4; ++j)
                            acc[rh][ch][i][j] += ar[rh][i] * br[ch][j];
        }
        __syncthreads();
    }
#pragma unroll
    for (int rh = 0; rh < 2; ++rh)
#pragma unroll
        for (int i = 0; i < 4; ++i) {
            int row = row0 + rh * 64 + ty * 4 + i;
            if (row >= M) continue;
#pragma unroll
            for (int ch = 0; ch < 2; ++ch) {
                int col = col0 + ch * 64 + tx * 4;
                float4 v = make_float4(acc[rh][ch][i][0], acc[rh][ch][i][1],
                                       acc[rh][ch][i][2], acc[rh][ch][i][3]);
                if (bias) {
                    float4 bv = *reinterpret_cast<const float4*>(&bias[col]);
                    v.x += bv.x; v.y += bv.y; v.z += bv.z; v.w += bv.w;
                }
                *reinterpret_cast<float4*>(&out[(long)row * CH + col]) = v;
            }
        }
}

// ---------------- E0-graph GCN aggregation via CSR (f64 acc: memory-bound, keeps atomic-order noise sub-ulp) ----------------
__global__ __launch_bounds__(256) void agg_e0(
    const float* __restrict__ h, const int* __restrict__ rowptr,
    const int* __restrict__ colsrc, const double* __restrict__ inv,
    const float* __restrict__ bias, float* __restrict__ out, int n)
{
    __shared__ int s_src[256];
    __shared__ double s_nrm[256];
    int i = blockIdx.x, c = threadIdx.x;
    int r0 = rowptr[i], r1 = rowptr[i + 1];
    double invd = inv[i];
    double acc = (double)h[(long)i * CH + c] * (invd * invd);  // self loop
    for (int base = r0; base < r1; base += 256) {
        int m = min(256, r1 - base);
        __syncthreads();
        if (c < m) {
            int s = colsrc[base + c];
            s_src[c] = s;
            s_nrm[c] = invd * inv[s];
        }
        __syncthreads();
        for (int j = 0; j < m; ++j)
            acc += (double)h[(long)s_src[j] * CH + c] * s_nrm[j];
    }
    double v = acc + (double)bias[c];
    out[(long)i * CH + c] = (float)fmax(v, 0.0);
}

// ---------------- KNN-graph aggregation: mean over (k neighbors + self), f64 acc (memory-bound) ----------------
__global__ void agg_knn(const float* __restrict__ h, const int* __restrict__ idx,
                        const float* __restrict__ b, float* __restrict__ out,
                        int n, int k, double s) {
    int i = blockIdx.x, c = threadIdx.x;
    double acc = (double)h[(long)i * CH + c];
    for (int j = 0; j < k; ++j) {
        int nb = idx[i * k + j];
        acc += (double)h[(long)nb * CH + c];
    }
    double v = acc * s + (double)b[c];
    out[(long)i * CH + c] = (float)fmax(v, 0.0);
}

// ---------------- brute-force KNN ----------------
// Distance formulas FROZEN (match golden, R7):
//   sq  = fma(y, y, round(x*x));  dot = fma(qy, py, round(qx*px));  d = fma(-2, dot, round(sq_q+sq_j))
// Selection: per-lane sorted top-K (strict '<', j ascending per lane = lex (d, idx) exact) with an
// additional wave-global threshold thrG = wave_min(bd[K-1]): since the min-achieving lane holds K
// entries with d <= thrG, global K-th dist <= thrG at all times, and every final top-K member has
// d <= final K-th <= thrG, so filtering with d <= thrG never drops a final member. EXACT.
template <int K>
__global__ __launch_bounds__(64) void knn_kernel(const float* __restrict__ pos, int n,
                                                 int* __restrict__ outIdx) {
    const float INF = __int_as_float(0x7f800000);
    int q = blockIdx.x;
    int lane = threadIdx.x;
    const float2* p2 = (const float2*)pos;
    const float4* p4 = (const float4*)pos;
    float2 qp = p2[q];
    float sqq = __fmaf_rn(qp.y, qp.y, __fmul_rn(qp.x, qp.x));
    float bd[K];
    int bi[K];
#pragma unroll
    for (int t = 0; t < K; ++t) { bd[t] = INF; bi[t] = 0x7fffffff; }
    float thrG = INF;
    for (int jj = lane * 2; jj < n; jj += 128) {
        float4 pp = p4[jj >> 1];  // points jj (x,y) and jj+1 (z,w)
#pragma unroll
        for (int c = 0; c < 2; ++c) {
            int j = jj + c;
            float px = c ? pp.z : pp.x;
            float py = c ? pp.w : pp.y;
            float sqj = __fmaf_rn(py, py, __fmul_rn(px, px));
            float dot = __fmaf_rn(qp.y, py, __fmul_rn(qp.x, px));
            float t1  = __fadd_rn(sqq, sqj);
            float d   = __fmaf_rn(-2.0f, dot, t1);
            d = (j == q) ? INF : d;
            if (d < bd[K - 1] && d <= thrG) {
                bd[K - 1] = d; bi[K - 1] = j;
#pragma unroll
                for (int t = K - 1; t > 0; --t) {
                    if (bd[t] < bd[t - 1]) {
                        float td = bd[t]; bd[t] = bd[t - 1]; bd[t - 1] = td;
                        int ti = bi[t]; bi[t] = bi[t - 1]; bi[t - 1] = ti;
                    }
                }
            }
        }
        // refresh wave-global threshold (upper bound on global K-th distance)
        float m = bd[K - 1];
#pragma unroll
        for (int off = 32; off; off >>= 1) {
            float o = __shfl_xor(m, off, 64);
            m = o < m ? o : m;
        }
        thrG = m;
    }
    // global merge: K rounds of 64-lane lex min; winner pops its head
    for (int r = 0; r < K; ++r) {
        float md = bd[0];
        int mi = bi[0];
#pragma unroll
        for (int off = 32; off; off >>= 1) {
            float od = __shfl_xor(md, off, 64);
            int oi = __shfl_xor(mi, off, 64);
            if (od < md || (od == md && oi < mi)) { md = od; mi = oi; }
        }
        if (md == bd[0] && mi == bi[0]) {
#pragma unroll
            for (int t = 0; t < K - 1; ++t) { bd[t] = bd[t + 1]; bi[t] = bi[t + 1]; }
            bd[K - 1] = INF; bi[K - 1] = 0x7fffffff;
        }
        if (lane == 0) outIdx[q * K + r] = mi;
    }
}

// ---------------- gathers / scatters ----------------
__global__ void gather_pos(const float* __restrict__ pos, const int* __restrict__ perm,
                           float* __restrict__ out, int m) {
    int i = blockIdx.x * blockDim.x + threadIdx.x;
    if (i < m) {
        int p = perm[i];
        ((float2*)out)[i] = ((const float2*)pos)[p];
    }
}
// dst[perm[i]] = src[perm[i]]  (mask rows; dst pre-zeroed)
__global__ void copy_rows(const float* __restrict__ srcb, const int* __restrict__ perm,
                          float* __restrict__ dst, int m) {
    int i = blockIdx.x, c = threadIdx.x;
    int r = perm[i];
    dst[(long)r * CH + c] = srcb[(long)r * CH + c];
}
// dst[perm[i]] = src[i]  (unpool scatter; dst pre-zeroed)
__global__ void scatter_rows(const float* __restrict__ srcb, const int* __restrict__ perm,
                             float* __restrict__ dst, int m) {
    int i = blockIdx.x, c = threadIdx.x;
    dst[(long)perm[i] * CH + c] = srcb[(long)i * CH + c];
}

extern "C" void kernel_launch(void* const* d_in, const int* in_sizes, int n_in,
                              void* d_out, int out_size, void* d_ws, size_t ws_size,
                              hipStream_t stream) {
    const float* x    = (const float*)d_in[0];
    const float* pos  = (const float*)d_in[1];
    const int*   ei   = (const int*)d_in[2];   // [2, E0]: src = ei[0:E0), dst = ei[E0:2E0)
    const int*   perm1 = (const int*)d_in[3];
    const int*   perm2 = (const int*)d_in[4];
    const int*   perm3 = (const int*)d_in[5];
    const float* Wd0 = (const float*)d_in[6],  *bd0 = (const float*)d_in[7];
    const float* Wd1 = (const float*)d_in[8],  *bd1 = (const float*)d_in[9];
    const float* Wd2 = (const float*)d_in[10], *bd2 = (const float*)d_in[11];
    const float* Wu0 = (const float*)d_in[12], *bu0 = (const float*)d_in[13];
    const float* Wu1 = (const float*)d_in[14], *bu1 = (const float*)d_in[15];
    const float* Wu2 = (const float*)d_in[16], *bu2 = (const float*)d_in[17];
    const float* Wlin = (const float*)d_in[18], *blin = (const float*)d_in[19];
    float* out = (float*)d_out;  // doubles as scratch B (fully rewritten every call)

    // workspace carve — float arrays first to keep 16B alignment for float4 loads
    double* inv0 = (double*)d_ws;                 // N0 doubles (320000 B, 16B-aligned)
    float* pos1 = (float*)(inv0 + N0);            // N1*2 floats
    float* pos2 = pos1 + N1 * 2;                  // N2*2 floats
    float* A   = pos2 + N2 * 2;                   // N0*CH
    float* C_  = A + (long)N0 * CH;               // N1*CH
    float* D_  = C_ + (long)N1 * CH;              // N1*CH
    int* degI   = (int*)(D_ + (long)N1 * CH);     // N0
    int* rowptr = degI + N0;                      // N0+1
    int* cursor = rowptr + N0 + 1;                // N0
    int* colsrc = cursor + N0;                    // E0
    int* idx1   = colsrc + E0;                    // N1*6
    int* idx2   = idx1 + N1 * 6;                  // N2*7
    int* incl   = idx2 + N2 * 7;                  // N0 (scan stage buffer)
    int* bsum   = incl + N0;                      // NBLK
    float* B = out;

    const int* e_src = ei;
    const int* e_dst = ei + E0;

    // ---- CSR + norms for the input graph ----
    hipMemsetAsync(degI, 0, (size_t)N0 * sizeof(int), stream);
    count_deg<<<(E0 + 255) / 256, 256, 0, stream>>>(e_dst, degI, E0);
    scan_blocks<<<NBLK, 256, 0, stream>>>(degI, incl, bsum, N0);
    scan_bsums<<<1, 256, 0, stream>>>(bsum, NBLK);
    finalize_rowptr<<<(N0 + 255) / 256, 256, 0, stream>>>(incl, bsum, rowptr, N0);
    copy_int<<<(N0 + 255) / 256, 256, 0, stream>>>(rowptr, cursor, N0);
    fill_csr<<<(E0 + 255) / 256, 256, 0, stream>>>(e_src, e_dst, cursor, colsrc, E0);
    make_inv<<<(N0 + 255) / 256, 256, 0, stream>>>(degI, inv0, N0);

    // ---- encoder level 0: conv(E0 graph) + relu ----
    gemm_f32<<<dim3((N0 + 127) / 128, 2), 256, 0, stream>>>(x, nullptr, Wd0, nullptr, A, N0, CIN);
    agg_e0<<<N0, 256, 0, stream>>>(A, rowptr, colsrc, inv0, bd0, B, N0);

    // ---- KNN level 1 ----
    gather_pos<<<(N1 + 255) / 256, 256, 0, stream>>>(pos, perm1, pos1, N1);
    knn_kernel<6><<<N1, 64, 0, stream>>>(pos1, N1, idx1);

    // ---- encoder level 1 (pool via gather) ----
    gemm_f32<<<dim3((N1 + 127) / 128, 2), 256, 0, stream>>>(B, perm1, Wd1, nullptr, C_, N1, CH);
    agg_knn<<<N1, 256, 0, stream>>>(C_, idx1, bd1, D_, N1, 6, 1.0 / 7.0);

    // ---- KNN level 2 ----
    gather_pos<<<(N2 + 255) / 256, 256, 0, stream>>>(pos1, perm2, pos2, N2);
    knn_kernel<7><<<N2, 64, 0, stream>>>(pos2, N2, idx2);

    // ---- encoder level 2 ----
    gemm_f32<<<dim3((N2 + 127) / 128, 2), 256, 0, stream>>>(D_, perm2, Wd2, nullptr, C_, N2, CH);
    agg_knn<<<N2, 256, 0, stream>>>(C_, idx2, bd2, D_, N2, 7, 1.0 / 8.0);  // Y2 in D_[0:N2)

    // ---- decoder level 0 (N2 nodes, knn2 graph): mask rows perm3 ----
    hipMemsetAsync(C_, 0, (size_t)N2 * CH * sizeof(float), stream);
    copy_rows<<<N3, 256, 0, stream>>>(D_, perm3, C_, N3);
    gemm_f32<<<dim3((N2 + 127) / 128, 2), 256, 0, stream>>>(C_, nullptr, Wu0, nullptr, D_, N2, CH);
    agg_knn<<<N2, 256, 0, stream>>>(D_, idx2, bu0, C_, N2, 7, 1.0 / 8.0);

    // ---- decoder level 1 (N1 nodes, knn1 graph) ----
    hipMemsetAsync(D_, 0, (size_t)N1 * CH * sizeof(float), stream);
    scatter_rows<<<N2, 256, 0, stream>>>(C_, perm2, D_, N2);
    gemm_f32<<<dim3((N1 + 127) / 128, 2), 256, 0, stream>>>(D_, nullptr, Wu1, nullptr, C_, N1, CH);
    agg_knn<<<N1, 256, 0, stream>>>(C_, idx1, bu1, D_, N1, 6, 1.0 / 7.0);

    // ---- decoder level 2 (N0 nodes, E0 graph) ----
    hipMemsetAsync(A, 0, (size_t)N0 * CH * sizeof(float), stream);
    scatter_rows<<<N1, 256, 0, stream>>>(D_, perm1, A, N1);
    gemm_f32<<<dim3((N0 + 127) / 128, 2), 256, 0, stream>>>(A, nullptr, Wu2, nullptr, B, N0, CH);
    agg_e0<<<N0, 256, 0, stream>>>(B, rowptr, colsrc, inv0, bu2, A, N0);

    // ---- final linear ----
    gemm_f32<<<dim3((N0 + 127) / 128, 2), 256, 0, stream>>>(A, nullptr, Wlin, blin, out, N0, CH);
}

// Round 12
// 634.493 us; speedup vs baseline: 1.1531x; 1.1531x over previous
//
#include <hip/hip_runtime.h>
#include <hip/hip_bf16.h>

#define N0 40000
#define N1 10000
#define N2 2500
#define N3 625
#define E0 240000
#define CIN 64
#define CH 256
#define NBLK ((N0 + 255) / 256)   // 157 scan blocks

// ---------------- degree / CSR build ----------------
__global__ void count_deg(const int* __restrict__ dst, int* __restrict__ deg, int e) {
    int i = blockIdx.x * blockDim.x + threadIdx.x;
    if (i < e) atomicAdd(&deg[dst[i]], 1);
}

// device-wide scan, stage 1: per-block inclusive scan + block sums
__global__ __launch_bounds__(256) void scan_blocks(const int* __restrict__ deg,
                                                   int* __restrict__ incl,
                                                   int* __restrict__ bsum, int n) {
    __shared__ int s[256];
    int i = blockIdx.x * 256 + threadIdx.x;
    s[threadIdx.x] = (i < n) ? deg[i] : 0;
    __syncthreads();
#pragma unroll
    for (int off = 1; off < 256; off <<= 1) {
        int t = (threadIdx.x >= off) ? s[threadIdx.x - off] : 0;
        __syncthreads();
        s[threadIdx.x] += t;
        __syncthreads();
    }
    if (i < n) incl[i] = s[threadIdx.x];
    if (threadIdx.x == 255) bsum[blockIdx.x] = s[255];
}

// stage 2: single-block inclusive scan of the block sums (NBLK <= 256)
__global__ __launch_bounds__(256) void scan_bsums(int* __restrict__ bsum, int nb) {
    __shared__ int s[256];
    s[threadIdx.x] = (threadIdx.x < nb) ? bsum[threadIdx.x] : 0;
    __syncthreads();
#pragma unroll
    for (int off = 1; off < 256; off <<= 1) {
        int t = (threadIdx.x >= off) ? s[threadIdx.x - off] : 0;
        __syncthreads();
        s[threadIdx.x] += t;
        __syncthreads();
    }
    if (threadIdx.x < nb) bsum[threadIdx.x] = s[threadIdx.x];
}

// stage 3: rowptr[0]=0; rowptr[i+1] = incl[i] + prefix(block sums)
__global__ void finalize_rowptr(const int* __restrict__ incl, const int* __restrict__ bsum,
                                int* __restrict__ rowptr, int n) {
    int i = blockIdx.x * blockDim.x + threadIdx.x;
    if (i == 0) rowptr[0] = 0;
    if (i < n) {
        int b = i >> 8;
        int off = b ? bsum[b - 1] : 0;
        rowptr[i + 1] = incl[i] + off;
    }
}

__global__ void copy_int(const int* __restrict__ a, int* __restrict__ b, int n) {
    int i = blockIdx.x * blockDim.x + threadIdx.x;
    if (i < n) b[i] = a[i];
}
__global__ void fill_csr(const int* __restrict__ src, const int* __restrict__ dst,
                         int* __restrict__ cursor, int* __restrict__ colsrc, int e) {
    int i = blockIdx.x * blockDim.x + threadIdx.x;
    if (i < e) {
        int d = dst[i];
        int p = atomicAdd(&cursor[d], 1);
        colsrc[p] = src[i];
    }
}
__global__ void make_inv(const int* __restrict__ deg, double* __restrict__ inv, int n) {
    int i = blockIdx.x * blockDim.x + threadIdx.x;
    if (i < n) inv[i] = 1.0 / sqrt((double)(deg[i] + 1));  // +1 self loop
}

// ---------------- f32 GEMM (f32 acc, vectorized LDS): out[M x 256] = A[gidx[M] x K] @ W[K x 256] (+bias) ----------------
__global__ __launch_bounds__(256) void gemm_f32(
    const float* __restrict__ A, const int* __restrict__ gidx,
    const float* __restrict__ W, const float* __restrict__ bias,
    float* __restrict__ out, int M, int K)
{
    __shared__ float As[16][68];   // [k][row], 68-stride keeps 16B alignment, breaks bank powers
    __shared__ float Bs[16][68];   // [k][col]
    const int tid = threadIdx.x;
    const int tx = tid & 15, ty = tid >> 4;
    const int row0 = blockIdx.x * 64, col0 = blockIdx.y * 64;
    const int sr = tid >> 2;            // 0..63 (row within tile)
    const int skq = (tid & 3) * 4;      // k-quad within 16-k panel
    const int bkk = tid >> 4;           // 0..15 (k for B staging)
    const int bc4 = (tid & 15) * 4;     // col-quad for B staging
    const int arow = row0 + sr;
    const bool rowok = arow < M;
    long arr = 0;
    if (rowok) arr = (long)(gidx ? gidx[arow] : arow) * K;

    float acc[4][4] = {};
    for (int k0 = 0; k0 < K; k0 += 16) {
        float4 av = make_float4(0.f, 0.f, 0.f, 0.f);
        if (rowok) av = *reinterpret_cast<const float4*>(&A[arr + k0 + skq]);
        As[skq + 0][sr] = av.x;
        As[skq + 1][sr] = av.y;
        As[skq + 2][sr] = av.z;
        As[skq + 3][sr] = av.w;
        float4 bv = *reinterpret_cast<const float4*>(&W[(long)(k0 + bkk) * CH + col0 + bc4]);
        *reinterpret_cast<float4*>(&Bs[bkk][bc4]) = bv;
        __syncthreads();
#pragma unroll
        for (int kk = 0; kk < 16; ++kk) {
            float4 a4 = *reinterpret_cast<const float4*>(&As[kk][ty * 4]);
            float4 b4 = *reinterpret_cast<const float4*>(&Bs[kk][tx * 4]);
            float a[4] = {a4.x, a4.y, a4.z, a4.w};
            float b[4] = {b4.x, b4.y, b4.z, b4.w};
#pragma unroll
            for (int i = 0; i < 4; i++)
#pragma unroll
                for (int j = 0; j < 4; j++) acc[i][j] += a[i] * b[j];
        }
        __syncthreads();
    }
#pragma unroll
    for (int i = 0; i < 4; i++) {
        int row = row0 + ty * 4 + i;
        if (row >= M) continue;
#pragma unroll
        for (int j = 0; j < 4; j++) {
            int col = col0 + tx * 4 + j;
            float v = acc[i][j];
            if (bias) v += bias[col];
            out[(long)row * CH + col] = v;
        }
    }
}

// ---------------- E0-graph GCN aggregation via CSR (f64 acc: memory-bound, keeps atomic-order noise sub-ulp) ----------------
__global__ __launch_bounds__(256) void agg_e0(
    const float* __restrict__ h, const int* __restrict__ rowptr,
    const int* __restrict__ colsrc, const double* __restrict__ inv,
    const float* __restrict__ bias, float* __restrict__ out, int n)
{
    __shared__ int s_src[256];
    __shared__ double s_nrm[256];
    int i = blockIdx.x, c = threadIdx.x;
    int r0 = rowptr[i], r1 = rowptr[i + 1];
    double invd = inv[i];
    double acc = (double)h[(long)i * CH + c] * (invd * invd);  // self loop
    for (int base = r0; base < r1; base += 256) {
        int m = min(256, r1 - base);
        __syncthreads();
        if (c < m) {
            int s = colsrc[base + c];
            s_src[c] = s;
            s_nrm[c] = invd * inv[s];
        }
        __syncthreads();
        for (int j = 0; j < m; ++j)
            acc += (double)h[(long)s_src[j] * CH + c] * s_nrm[j];
    }
    double v = acc + (double)bias[c];
    out[(long)i * CH + c] = (float)fmax(v, 0.0);
}

// ---------------- KNN-graph aggregation: mean over (k neighbors + self), f64 acc (memory-bound) ----------------
__global__ void agg_knn(const float* __restrict__ h, const int* __restrict__ idx,
                        const float* __restrict__ b, float* __restrict__ out,
                        int n, int k, double s) {
    int i = blockIdx.x, c = threadIdx.x;
    double acc = (double)h[(long)i * CH + c];
    for (int j = 0; j < k; ++j) {
        int nb = idx[i * k + j];
        acc += (double)h[(long)nb * CH + c];
    }
    double v = acc * s + (double)b[c];
    out[(long)i * CH + c] = (float)fmax(v, 0.0);
}

// ---------------- brute-force KNN ----------------
// Distance formulas FROZEN (match golden, R7):
//   sq  = fma(y, y, round(x*x));  dot = fma(qy, py, round(qx*px));  d = fma(-2, dot, round(sq_q+sq_j))
// Selection: per-lane sorted top-K (strict '<', j ascending per lane = lex (d, idx) exact), plus a
// wave-global threshold thrG refreshed every 4 iterations. Exactness: thrG equals wave_min(bd[K-1])
// at an earlier time; that lane then held K candidates all <= thrG, so global K-th <= thrG then and
// forever after (monotone). Any final top-K member has d <= final K-th <= thrG, and '<=' keeps
// boundary ties, so the filter never drops a final member. Stale thrG is a looser bound -> still exact.
template <int K>
__global__ __launch_bounds__(64) void knn_kernel(const float* __restrict__ pos, int n,
                                                 int* __restrict__ outIdx) {
    const float INF = __int_as_float(0x7f800000);
    int q = blockIdx.x;
    int lane = threadIdx.x;
    const float2* p2 = (const float2*)pos;
    const float4* p4 = (const float4*)pos;
    float2 qp = p2[q];
    float sqq = __fmaf_rn(qp.y, qp.y, __fmul_rn(qp.x, qp.x));
    float bd[K];
    int bi[K];
#pragma unroll
    for (int t = 0; t < K; ++t) { bd[t] = INF; bi[t] = 0x7fffffff; }
    float thrG = INF;
    int m = 0;
    for (int jj = lane * 2; jj < n; jj += 128, ++m) {
        float4 pp = p4[jj >> 1];  // points jj (x,y) and jj+1 (z,w)
#pragma unroll
        for (int c = 0; c < 2; ++c) {
            int j = jj + c;
            float px = c ? pp.z : pp.x;
            float py = c ? pp.w : pp.y;
            float sqj = __fmaf_rn(py, py, __fmul_rn(px, px));
            float dot = __fmaf_rn(qp.y, py, __fmul_rn(qp.x, px));
            float t1  = __fadd_rn(sqq, sqj);
            float d   = __fmaf_rn(-2.0f, dot, t1);
            d = (j == q) ? INF : d;
            if (d < bd[K - 1] && d <= thrG) {
                bd[K - 1] = d; bi[K - 1] = j;
#pragma unroll
                for (int t = K - 1; t > 0; --t) {
                    if (bd[t] < bd[t - 1]) {
                        float td = bd[t]; bd[t] = bd[t - 1]; bd[t - 1] = td;
                        int ti = bi[t]; bi[t] = bi[t - 1]; bi[t - 1] = ti;
                    }
                }
            }
        }
        if ((m & 3) == 3) {  // periodic threshold refresh, off the per-iteration critical path
            float mm = bd[K - 1];
#pragma unroll
            for (int off = 32; off; off >>= 1) {
                float o = __shfl_xor(mm, off, 64);
                mm = o < mm ? o : mm;
            }
            thrG = mm;
        }
    }
    // global merge: K rounds of 64-lane lex min; winner pops its head
    for (int r = 0; r < K; ++r) {
        float md = bd[0];
        int mi = bi[0];
#pragma unroll
        for (int off = 32; off; off >>= 1) {
            float od = __shfl_xor(md, off, 64);
            int oi = __shfl_xor(mi, off, 64);
            if (od < md || (od == md && oi < mi)) { md = od; mi = oi; }
        }
        if (md == bd[0] && mi == bi[0]) {
#pragma unroll
            for (int t = 0; t < K - 1; ++t) { bd[t] = bd[t + 1]; bi[t] = bi[t + 1]; }
            bd[K - 1] = INF; bi[K - 1] = 0x7fffffff;
        }
        if (lane == 0) outIdx[q * K + r] = mi;
    }
}

// ---------------- gathers / scatters ----------------
__global__ void gather_pos(const float* __restrict__ pos, const int* __restrict__ perm,
                           float* __restrict__ out, int m) {
    int i = blockIdx.x * blockDim.x + threadIdx.x;
    if (i < m) {
        int p = perm[i];
        ((float2*)out)[i] = ((const float2*)pos)[p];
    }
}
// dst[perm[i]] = src[perm[i]]  (mask rows; dst pre-zeroed)
__global__ void copy_rows(const float* __restrict__ srcb, const int* __restrict__ perm,
                          float* __restrict__ dst, int m) {
    int i = blockIdx.x, c = threadIdx.x;
    int r = perm[i];
    dst[(long)r * CH + c] = srcb[(long)r * CH + c];
}
// dst[perm[i]] = src[i]  (unpool scatter; dst pre-zeroed)
__global__ void scatter_rows(const float* __restrict__ srcb, const int* __restrict__ perm,
                             float* __restrict__ dst, int m) {
    int i = blockIdx.x, c = threadIdx.x;
    dst[(long)perm[i] * CH + c] = srcb[(long)i * CH + c];
}

extern "C" void kernel_launch(void* const* d_in, const int* in_sizes, int n_in,
                              void* d_out, int out_size, void* d_ws, size_t ws_size,
                              hipStream_t stream) {
    const float* x    = (const float*)d_in[0];
    const float* pos  = (const float*)d_in[1];
    const int*   ei   = (const int*)d_in[2];   // [2, E0]: src = ei[0:E0), dst = ei[E0:2E0)
    const int*   perm1 = (const int*)d_in[3];
    const int*   perm2 = (const int*)d_in[4];
    const int*   perm3 = (const int*)d_in[5];
    const float* Wd0 = (const float*)d_in[6],  *bd0 = (const float*)d_in[7];
    const float* Wd1 = (const float*)d_in[8],  *bd1 = (const float*)d_in[9];
    const float* Wd2 = (const float*)d_in[10], *bd2 = (const float*)d_in[11];
    const float* Wu0 = (const float*)d_in[12], *bu0 = (const float*)d_in[13];
    const float* Wu1 = (const float*)d_in[14], *bu1 = (const float*)d_in[15];
    const float* Wu2 = (const float*)d_in[16], *bu2 = (const float*)d_in[17];
    const float* Wlin = (const float*)d_in[18], *blin = (const float*)d_in[19];
    float* out = (float*)d_out;  // doubles as scratch B (fully rewritten every call)

    // workspace carve — float arrays first to keep 16B alignment for float4 loads
    double* inv0 = (double*)d_ws;                 // N0 doubles (320000 B, 16B-aligned)
    float* pos1 = (float*)(inv0 + N0);            // N1*2 floats
    float* pos2 = pos1 + N1 * 2;                  // N2*2 floats
    float* A   = pos2 + N2 * 2;                   // N0*CH
    float* C_  = A + (long)N0 * CH;               // N1*CH
    float* D_  = C_ + (long)N1 * CH;              // N1*CH
    int* degI   = (int*)(D_ + (long)N1 * CH);     // N0
    int* rowptr = degI + N0;                      // N0+1
    int* cursor = rowptr + N0 + 1;                // N0
    int* colsrc = cursor + N0;                    // E0
    int* idx1   = colsrc + E0;                    // N1*6
    int* idx2   = idx1 + N1 * 6;                  // N2*7
    int* incl   = idx2 + N2 * 7;                  // N0 (scan stage buffer)
    int* bsum   = incl + N0;                      // NBLK
    float* B = out;

    const int* e_src = ei;
    const int* e_dst = ei + E0;

    // ---- CSR + norms for the input graph ----
    hipMemsetAsync(degI, 0, (size_t)N0 * sizeof(int), stream);
    count_deg<<<(E0 + 255) / 256, 256, 0, stream>>>(e_dst, degI, E0);
    scan_blocks<<<NBLK, 256, 0, stream>>>(degI, incl, bsum, N0);
    scan_bsums<<<1, 256, 0, stream>>>(bsum, NBLK);
    finalize_rowptr<<<(N0 + 255) / 256, 256, 0, stream>>>(incl, bsum, rowptr, N0);
    copy_int<<<(N0 + 255) / 256, 256, 0, stream>>>(rowptr, cursor, N0);
    fill_csr<<<(E0 + 255) / 256, 256, 0, stream>>>(e_src, e_dst, cursor, colsrc, E0);
    make_inv<<<(N0 + 255) / 256, 256, 0, stream>>>(degI, inv0, N0);

    // ---- encoder level 0: conv(E0 graph) + relu ----
    gemm_f32<<<dim3((N0 + 63) / 64, 4), 256, 0, stream>>>(x, nullptr, Wd0, nullptr, A, N0, CIN);
    agg_e0<<<N0, 256, 0, stream>>>(A, rowptr, colsrc, inv0, bd0, B, N0);

    // ---- KNN level 1 ----
    gather_pos<<<(N1 + 255) / 256, 256, 0, stream>>>(pos, perm1, pos1, N1);
    knn_kernel<6><<<N1, 64, 0, stream>>>(pos1, N1, idx1);

    // ---- encoder level 1 (pool via gather) ----
    gemm_f32<<<dim3((N1 + 63) / 64, 4), 256, 0, stream>>>(B, perm1, Wd1, nullptr, C_, N1, CH);
    agg_knn<<<N1, 256, 0, stream>>>(C_, idx1, bd1, D_, N1, 6, 1.0 / 7.0);

    // ---- KNN level 2 ----
    gather_pos<<<(N2 + 255) / 256, 256, 0, stream>>>(pos1, perm2, pos2, N2);
    knn_kernel<7><<<N2, 64, 0, stream>>>(pos2, N2, idx2);

    // ---- encoder level 2 ----
    gemm_f32<<<dim3((N2 + 63) / 64, 4), 256, 0, stream>>>(D_, perm2, Wd2, nullptr, C_, N2, CH);
    agg_knn<<<N2, 256, 0, stream>>>(C_, idx2, bd2, D_, N2, 7, 1.0 / 8.0);  // Y2 in D_[0:N2)

    // ---- decoder level 0 (N2 nodes, knn2 graph): mask rows perm3 ----
    hipMemsetAsync(C_, 0, (size_t)N2 * CH * sizeof(float), stream);
    copy_rows<<<N3, 256, 0, stream>>>(D_, perm3, C_, N3);
    gemm_f32<<<dim3((N2 + 63) / 64, 4), 256, 0, stream>>>(C_, nullptr, Wu0, nullptr, D_, N2, CH);
    agg_knn<<<N2, 256, 0, stream>>>(D_, idx2, bu0, C_, N2, 7, 1.0 / 8.0);

    // ---- decoder level 1 (N1 nodes, knn1 graph) ----
    hipMemsetAsync(D_, 0, (size_t)N1 * CH * sizeof(float), stream);
    scatter_rows<<<N2, 256, 0, stream>>>(C_, perm2, D_, N2);
    gemm_f32<<<dim3((N1 + 63) / 64, 4), 256, 0, stream>>>(D_, nullptr, Wu1, nullptr, C_, N1, CH);
    agg_knn<<<N1, 256, 0, stream>>>(C_, idx1, bu1, D_, N1, 6, 1.0 / 7.0);

    // ---- decoder level 2 (N0 nodes, E0 graph) ----
    hipMemsetAsync(A, 0, (size_t)N0 * CH * sizeof(float), stream);
    scatter_rows<<<N1, 256, 0, stream>>>(D_, perm1, A, N1);
    gemm_f32<<<dim3((N0 + 63) / 64, 4), 256, 0, stream>>>(A, nullptr, Wu2, nullptr, B, N0, CH);
    agg_e0<<<N0, 256, 0, stream>>>(B, rowptr, colsrc, inv0, bu2, A, N0);

    // ---- final linear ----
    gemm_f32<<<dim3((N0 + 63) / 64, 4), 256, 0, stream>>>(A, nullptr, Wlin, blin, out, N0, CH);
}